// Round 6
// baseline (28.544 us; speedup 1.0000x reference)
//
#include <hip/hip_runtime.h>

// Problem dims (fixed by the reference)
#define LW   16      // chars per word (max)
#define GD   300     // glove dim
#define CEM  64      // char emb dim
#define OD   100     // out dim of conv/linear
#define NCH  128     // char vocab
#define NW   (32 * 512)   // 16384 words
#define TROW 128     // padded T row (floats)

// d_ws layout: Tpad[128][128] at [0 .. 16384) (cols 0..99 valid), c[100] at [16384..16484)
//   T[ch][o] = sum_j lin_w[o,j] * (sum_e conv_w[j,e] * char_table[ch,e])
//   c[o]     = lin_b[o] + sum_j lin_w[o,j] * conv_b[j]
// One block per char. Weights staged to LDS coalesced; padded rows -> conflict-free reads.
__global__ __launch_bounds__(128) void precompute_T(
        const float* __restrict__ char_table, const float* __restrict__ conv_w,
        const float* __restrict__ conv_b,     const float* __restrict__ lin_w,
        const float* __restrict__ lin_b,      float* __restrict__ ws) {
    __shared__ float cwS[OD * 65];    // conv_w row j at j*65  (65 % 32 coprime -> no conflicts)
    __shared__ float lwS[OD * 101];   // lin_w  row o at o*101 (101 % 32 = 5, coprime)
    __shared__ float ceS[CEM];
    __shared__ float U[OD];
    const int t  = threadIdx.x;
    const int ch = blockIdx.x;

    // coalesced global reads -> padded LDS rows
    for (int n = t; n < OD * CEM; n += 128)
        cwS[(n >> 6) * 65 + (n & 63)] = conv_w[n];
    for (int n = t; n < OD * OD; n += 128)
        lwS[(n / 100) * 101 + (n % 100)] = lin_w[n];
    if (t < CEM) ceS[t] = char_table[ch * CEM + t];
    __syncthreads();

    if (t < OD) {
        const float* cw = cwS + t * 65;
        float a0 = 0.f, a1 = 0.f, a2 = 0.f, a3 = 0.f;
        #pragma unroll
        for (int e = 0; e < CEM; e += 4) {
            a0 = fmaf(cw[e + 0], ceS[e + 0], a0);
            a1 = fmaf(cw[e + 1], ceS[e + 1], a1);
            a2 = fmaf(cw[e + 2], ceS[e + 2], a2);
            a3 = fmaf(cw[e + 3], ceS[e + 3], a3);
        }
        U[t] = (a0 + a1) + (a2 + a3);
    }
    __syncthreads();

    if (t < OD) {
        const float* lw = lwS + t * 101;
        float a0 = 0.f, a1 = 0.f, a2 = 0.f, a3 = 0.f;
        #pragma unroll 5
        for (int j = 0; j < OD; j += 4) {
            a0 = fmaf(lw[j + 0], U[j + 0], a0);
            a1 = fmaf(lw[j + 1], U[j + 1], a1);
            a2 = fmaf(lw[j + 2], U[j + 2], a2);
            a3 = fmaf(lw[j + 3], U[j + 3], a3);
        }
        ws[ch * TROW + t] = (a0 + a1) + (a2 + a3);   // coalesced padded T row

        if (ch == 0) {                               // bias c, once
            float b0 = lin_b[t], b1 = 0.f, b2 = 0.f, b3 = 0.f;
            #pragma unroll 5
            for (int j = 0; j < OD; j += 4) {
                b0 = fmaf(lw[j + 0], conv_b[j + 0], b0);
                b1 = fmaf(lw[j + 1], conv_b[j + 1], b1);
                b2 = fmaf(lw[j + 2], conv_b[j + 2], b2);
                b3 = fmaf(lw[j + 3], conv_b[j + 3], b3);
            }
            ws[NCH * TROW + t] = (b0 + b1) + (b2 + b3);
        }
    }
}

// One wave per word, 4 waves/block. Lane l (<50) owns outputs o=2l,2l+1 (float2).
// T rows read as float2 (one load per char instead of two); char-groups use
// wave-uniform full/partial split so full groups skip the cndmasks.
__global__ __launch_bounds__(256) void fused_embed(
        const int*   __restrict__ word_tokens,
        const int*   __restrict__ char_ids,
        const int*   __restrict__ char_lens,
        const float* __restrict__ glove,
        const float* __restrict__ ws,
        float*       __restrict__ out) {
    const int wave = threadIdx.x >> 6;
    const int lane = threadIdx.x & 63;
    const int word = blockIdx.x * 4 + wave;

    const int tok = word_tokens[word];              // wave-uniform
    const int len = char_lens[word];                // wave-uniform, >= 1

    const int4* cid4 = (const int4*)(char_ids + (size_t)word * LW);
    const int4 i0 = cid4[0], i1 = cid4[1], i2 = cid4[2], i3 = cid4[3];

    // glove passthrough: 75 float4, coalesced
    const float4* g4 = (const float4*)(glove + (size_t)tok * GD);
    float4 g0 = g4[lane];
    float4 g1;
    const bool tail = lane < (GD / 4 - 64);         // lanes 0..10
    if (tail) g1 = g4[64 + lane];

    // bias (masked: lanes >= 50 would read past the written region)
    const bool act = lane < OD / 2;                 // lanes 0..49
    float2 cb = {0.f, 0.f};
    if (act) cb = ((const float2*)(ws + NCH * TROW))[lane];

    float2 acc = {0.f, 0.f};

    // group 0 loads issued unconditionally (len >= 1); junk lanes stay inside Tpad.
#define TROWP(id) ((const float2*)(ws + ((id) << 7)))
#define LOADG(iv, a, b, c, d) \
    float2 a = TROWP((iv).x)[lane], b = TROWP((iv).y)[lane], \
           c = TROWP((iv).z)[lane], d = TROWP((iv).w)[lane];
#define ADDF(a, b, c, d) { \
    acc.x += ((a.x + b.x) + (c.x + d.x)); \
    acc.y += ((a.y + b.y) + (c.y + d.y)); }
#define ADDP(base, a, b, c, d) { \
    acc.x += ((base) + 0 < len) ? a.x : 0.f;  acc.y += ((base) + 0 < len) ? a.y : 0.f; \
    acc.x += ((base) + 1 < len) ? b.x : 0.f;  acc.y += ((base) + 1 < len) ? b.y : 0.f; \
    acc.x += ((base) + 2 < len) ? c.x : 0.f;  acc.y += ((base) + 2 < len) ? c.y : 0.f; \
    acc.x += ((base) + 3 < len) ? d.x : 0.f;  acc.y += ((base) + 3 < len) ? d.y : 0.f; }

    {
        LOADG(i0, v0, v1, v2, v3)
        if (len >= 4) ADDF(v0, v1, v2, v3) else ADDP(0, v0, v1, v2, v3)
    }
    if (len > 4) {
        LOADG(i1, v0, v1, v2, v3)
        if (len >= 8) ADDF(v0, v1, v2, v3) else ADDP(4, v0, v1, v2, v3)
    }
    if (len > 8) {
        LOADG(i2, v0, v1, v2, v3)
        if (len >= 12) ADDF(v0, v1, v2, v3) else ADDP(8, v0, v1, v2, v3)
    }
    if (len > 12) {
        LOADG(i3, v0, v1, v2, v3)
        if (len >= 16) ADDF(v0, v1, v2, v3) else ADDP(12, v0, v1, v2, v3)
    }
#undef TROWP
#undef LOADG
#undef ADDF
#undef ADDP

    // glove store (after T loads are issued)
    float4* d4 = (float4*)(out + (size_t)word * (GD + OD));
    d4[lane] = g0;
    if (tail) d4[64 + lane] = g1;

    const float inv = 1.f / (float)len;
    float2 r;
    r.x = fmaf(acc.x, inv, cb.x);
    r.y = fmaf(acc.y, inv, cb.y);
    if (act) {
        float2* co2 = (float2*)(out + (size_t)word * (GD + OD) + GD);
        co2[lane] = r;                               // 400 B coalesced
    }
}

extern "C" void kernel_launch(void* const* d_in, const int* in_sizes, int n_in,
                              void* d_out, int out_size, void* d_ws, size_t ws_size,
                              hipStream_t stream) {
    const int*   word_tokens = (const int*)  d_in[0];
    const int*   char_ids    = (const int*)  d_in[1];
    const int*   char_lens   = (const int*)  d_in[2];
    const float* glove       = (const float*)d_in[3];
    const float* char_table  = (const float*)d_in[4];
    const float* conv_w      = (const float*)d_in[5];
    const float* conv_b      = (const float*)d_in[6];
    const float* lin_w       = (const float*)d_in[7];
    const float* lin_b       = (const float*)d_in[8];
    float* out = (float*)d_out;
    float* ws  = (float*)d_ws;   // needs 16484 floats ~= 66 KB

    precompute_T<<<NCH, 128, 0, stream>>>(char_table, conv_w, conv_b, lin_w, lin_b, ws);

    fused_embed<<<NW / 4, 256, 0, stream>>>(
        word_tokens, char_ids, char_lens, glove, ws, out);
}

// Round 7
// 25.493 us; speedup vs baseline: 1.1197x; 1.1197x over previous
//
#include <hip/hip_runtime.h>

// Problem dims (fixed by the reference)
#define LW   16      // chars per word (max)
#define GD   300     // glove dim
#define CEM  64      // char emb dim
#define OD   100     // out dim of conv/linear
#define NCH  128     // char vocab
#define NW   (32 * 512)   // 16384 words

// d_ws layout (floats):
//   [0     .. 12800)  T[128][100]   T[ch][o] = sum_e ce[ch][e] * Wc[e][o]
//   [12800 .. 12900)  c[100]        c[o] = lin_b[o] + sum_j lin_w[o,j]*conv_b[j]
//   [12900 .. 12928)  pad (fused's masked bias read touches up to 12927)
//   [12928 .. 19328)  Wc[64][100]   Wc[e][o] = sum_j lin_w[o,j]*conv_w[j,e]
//   [19328 .. 19456)  pad (K1's masked float2 read touches up to 19355)
#define WCOFF  12928
#define WSNEED 19456

// ---- K0: blocks 0..99 (o): Wc column; lane = e, conv_w coalesced, lin_w scalar.
//      block 100: bias c. 1 wave per block.
__global__ __launch_bounds__(64) void k_wc(
        const float* __restrict__ conv_w, const float* __restrict__ conv_b,
        const float* __restrict__ lin_w,  const float* __restrict__ lin_b,
        float* __restrict__ ws) {
    const int e = threadIdx.x;      // 0..63
    const int o = blockIdx.x;
    if (o < OD) {
        const float* lw = lin_w + o * OD;            // wave-uniform row
        float a0 = 0.f, a1 = 0.f, a2 = 0.f, a3 = 0.f;
        #pragma unroll 5
        for (int j = 0; j < OD; j += 4) {
            a0 = fmaf(lw[j + 0], conv_w[(j + 0) * CEM + e], a0);  // coalesced 256B
            a1 = fmaf(lw[j + 1], conv_w[(j + 1) * CEM + e], a1);
            a2 = fmaf(lw[j + 2], conv_w[(j + 2) * CEM + e], a2);
            a3 = fmaf(lw[j + 3], conv_w[(j + 3) * CEM + e], a3);
        }
        ws[WCOFF + e * OD + o] = (a0 + a1) + (a2 + a3);           // scattered store (ok)
    } else {
        // bias: thread e covers o' = e, and o' = 64+e for e < 36
        {
            const float* lw = lin_w + e * OD;
            float b0 = lin_b[e], b1 = 0.f, b2 = 0.f, b3 = 0.f;
            #pragma unroll 5
            for (int j = 0; j < OD; j += 4) {
                b0 = fmaf(lw[j + 0], conv_b[j + 0], b0);
                b1 = fmaf(lw[j + 1], conv_b[j + 1], b1);
                b2 = fmaf(lw[j + 2], conv_b[j + 2], b2);
                b3 = fmaf(lw[j + 3], conv_b[j + 3], b3);
            }
            ws[NCH * OD + e] = (b0 + b1) + (b2 + b3);
        }
        if (e < OD - 64) {
            const float* lw = lin_w + (64 + e) * OD;
            float b0 = lin_b[64 + e], b1 = 0.f, b2 = 0.f, b3 = 0.f;
            #pragma unroll 5
            for (int j = 0; j < OD; j += 4) {
                b0 = fmaf(lw[j + 0], conv_b[j + 0], b0);
                b1 = fmaf(lw[j + 1], conv_b[j + 1], b1);
                b2 = fmaf(lw[j + 2], conv_b[j + 2], b2);
                b3 = fmaf(lw[j + 3], conv_b[j + 3], b3);
            }
            ws[NCH * OD + 64 + e] = (b0 + b1) + (b2 + b3);
        }
    }
}

// ---- K1: block = ch; lane l < 50 owns T[ch][2l..2l+1]. Wc rows coalesced float2,
//      ce broadcast from LDS, T row stored coalesced.
__global__ __launch_bounds__(64) void k_T(
        const float* __restrict__ char_table, float* __restrict__ ws) {
    __shared__ float ceS[CEM];
    const int l  = threadIdx.x;
    const int ch = blockIdx.x;
    ceS[l] = char_table[ch * CEM + l];               // 256B coalesced
    __syncthreads();
    float2 acc = {0.f, 0.f};
    #pragma unroll 8
    for (int e = 0; e < CEM; ++e) {
        const float  m = ceS[e];                     // LDS broadcast
        const float2 w = ((const float2*)(ws + WCOFF + e * OD))[l];  // 400B coalesced; l>=50 junk (padded, masked)
        acc.x = fmaf(m, w.x, acc.x);
        acc.y = fmaf(m, w.y, acc.y);
    }
    if (l < OD / 2)
        ((float2*)(ws + ch * OD))[l] = acc;          // coalesced T row
}

// ---- Fallback precompute (R5 verbatim): used if ws_size too small for Wc region.
__global__ __launch_bounds__(128) void precompute_T(
        const float* __restrict__ char_table, const float* __restrict__ conv_w,
        const float* __restrict__ conv_b,     const float* __restrict__ lin_w,
        const float* __restrict__ lin_b,      float* __restrict__ ws) {
    __shared__ float ceS[CEM];
    __shared__ float U[OD];
    const int t  = threadIdx.x;
    const int ch = blockIdx.x;

    if (t < CEM) ceS[t] = char_table[ch * CEM + t];
    __syncthreads();

    if (t < OD) {
        const float* cw = conv_w + t * CEM;
        float a0 = 0.f, a1 = 0.f, a2 = 0.f, a3 = 0.f;
        #pragma unroll
        for (int e = 0; e < CEM; e += 4) {
            a0 = fmaf(cw[e + 0], ceS[e + 0], a0);
            a1 = fmaf(cw[e + 1], ceS[e + 1], a1);
            a2 = fmaf(cw[e + 2], ceS[e + 2], a2);
            a3 = fmaf(cw[e + 3], ceS[e + 3], a3);
        }
        U[t] = (a0 + a1) + (a2 + a3);
    }
    __syncthreads();

    if (t < OD) {
        const float* lw = lin_w + t * OD;
        float a0 = 0.f, a1 = 0.f, a2 = 0.f, a3 = 0.f;
        #pragma unroll 5
        for (int j = 0; j < OD; j += 4) {
            a0 = fmaf(lw[j + 0], U[j + 0], a0);
            a1 = fmaf(lw[j + 1], U[j + 1], a1);
            a2 = fmaf(lw[j + 2], U[j + 2], a2);
            a3 = fmaf(lw[j + 3], U[j + 3], a3);
        }
        ws[ch * OD + t] = (a0 + a1) + (a2 + a3);

        if (ch == 0) {
            float b0 = lin_b[t], b1 = 0.f, b2 = 0.f, b3 = 0.f;
            #pragma unroll 5
            for (int j = 0; j < OD; j += 4) {
                b0 = fmaf(lw[j + 0], conv_b[j + 0], b0);
                b1 = fmaf(lw[j + 1], conv_b[j + 1], b1);
                b2 = fmaf(lw[j + 2], conv_b[j + 2], b2);
                b3 = fmaf(lw[j + 3], conv_b[j + 3], b3);
            }
            ws[NCH * OD + t] = (b0 + b1) + (b2 + b3);
        }
    }
}

// ---- fused_embed: R5 verbatim (known-good). One wave per word, 4 waves/block.
__global__ __launch_bounds__(256) void fused_embed(
        const int*   __restrict__ word_tokens,
        const int*   __restrict__ char_ids,
        const int*   __restrict__ char_lens,
        const float* __restrict__ glove,
        const float* __restrict__ ws,
        float*       __restrict__ out) {
    const int wave = threadIdx.x >> 6;
    const int lane = threadIdx.x & 63;
    const int word = blockIdx.x * 4 + wave;

    const int tok = word_tokens[word];              // wave-uniform
    const int len = char_lens[word];                // wave-uniform, >= 1

    const int4* cid4 = (const int4*)(char_ids + (size_t)word * LW);
    const int4 i0 = cid4[0], i1 = cid4[1], i2 = cid4[2], i3 = cid4[3];

    // glove passthrough: 75 float4, coalesced
    const float4* g4 = (const float4*)(glove + (size_t)tok * GD);
    float4 g0 = g4[lane];
    float4 g1;
    const bool tail = lane < (GD / 4 - 64);         // lanes 0..10
    if (tail) g1 = g4[64 + lane];
    float4* d4 = (float4*)(out + (size_t)word * (GD + OD));
    d4[lane] = g0;
    if (tail) d4[64 + lane] = g1;

    // bias (load early, hides under gather)
    const float cl = ws[NCH * OD + lane];                          // c[lane]
    const bool hi = lane < (OD - 64);                              // lanes 0..35
    const float chv = ws[NCH * OD + 64 + lane];                    // junk if !hi, masked later
    float acc0 = 0.f, acc1 = 0.f;

#define CGROUP(iv, base)                                                   \
    {                                                                      \
        const float* t0 = ws + (iv).x * OD;                                \
        const float* t1 = ws + (iv).y * OD;                                \
        const float* t2 = ws + (iv).z * OD;                                \
        const float* t3 = ws + (iv).w * OD;                                \
        float v0 = t0[lane], w0 = t0[64 + lane];                           \
        float v1 = t1[lane], w1 = t1[64 + lane];                           \
        float v2 = t2[lane], w2 = t2[64 + lane];                           \
        float v3 = t3[lane], w3 = t3[64 + lane];                           \
        acc0 += ((base) + 0 < len) ? v0 : 0.f;                             \
        acc1 += ((base) + 0 < len) ? w0 : 0.f;                             \
        acc0 += ((base) + 1 < len) ? v1 : 0.f;                             \
        acc1 += ((base) + 1 < len) ? w1 : 0.f;                             \
        acc0 += ((base) + 2 < len) ? v2 : 0.f;                             \
        acc1 += ((base) + 2 < len) ? w2 : 0.f;                             \
        acc0 += ((base) + 3 < len) ? v3 : 0.f;                             \
        acc1 += ((base) + 3 < len) ? w3 : 0.f;                             \
    }

    CGROUP(i0, 0)                       // len >= 1 always
    if (len > 4)  CGROUP(i1, 4)
    if (len > 8)  CGROUP(i2, 8)
    if (len > 12) CGROUP(i3, 12)
#undef CGROUP

    const float inv = 1.f / (float)len;
    float* co = out + (size_t)word * (GD + OD) + GD;
    co[lane] = fmaf(acc0, inv, cl);
    if (hi) co[64 + lane] = fmaf(acc1, inv, chv);
}

extern "C" void kernel_launch(void* const* d_in, const int* in_sizes, int n_in,
                              void* d_out, int out_size, void* d_ws, size_t ws_size,
                              hipStream_t stream) {
    const int*   word_tokens = (const int*)  d_in[0];
    const int*   char_ids    = (const int*)  d_in[1];
    const int*   char_lens   = (const int*)  d_in[2];
    const float* glove       = (const float*)d_in[3];
    const float* char_table  = (const float*)d_in[4];
    const float* conv_w      = (const float*)d_in[5];
    const float* conv_b      = (const float*)d_in[6];
    const float* lin_w       = (const float*)d_in[7];
    const float* lin_b       = (const float*)d_in[8];
    float* out = (float*)d_out;
    float* ws  = (float*)d_ws;

    if (ws_size >= (size_t)WSNEED * sizeof(float)) {
        k_wc<<<OD + 1, 64, 0, stream>>>(conv_w, conv_b, lin_w, lin_b, ws);
        k_T <<<NCH,    64, 0, stream>>>(char_table, ws);
    } else {
        precompute_T<<<NCH, 128, 0, stream>>>(char_table, conv_w, conv_b,
                                              lin_w, lin_b, ws);
    }

    fused_embed<<<NW / 4, 256, 0, stream>>>(
        word_tokens, char_ids, char_lens, glove, ws, out);
}

// Round 8
// 24.657 us; speedup vs baseline: 1.1576x; 1.0339x over previous
//
#include <hip/hip_runtime.h>

// Problem dims (fixed by the reference)
#define LW   16      // chars per word (max)
#define GD   300     // glove dim
#define CEM  64      // char emb dim
#define OD   100     // out dim of conv/linear
#define NCH  128     // char vocab
#define NW   (32 * 512)   // 16384 words

// d_ws layout (floats):
//   [0     .. 12800)  T[128][100]   T[ch][o] = sum_e ce[ch][e] * Wc[e][o]
//   [12800 .. 12900)  c[100]
//   [12900 .. 12928)  pad (junk-lane float2 bias reads touch up to 12927)
// needs 12928 floats = 51.7 KB of d_ws.

// Single precompute kernel (R5 verbatim — known-good, ~1-2 us over 128 CUs).
__global__ __launch_bounds__(128) void precompute_T(
        const float* __restrict__ char_table, const float* __restrict__ conv_w,
        const float* __restrict__ conv_b,     const float* __restrict__ lin_w,
        const float* __restrict__ lin_b,      float* __restrict__ ws) {
    __shared__ float ceS[CEM];
    __shared__ float U[OD];
    const int t  = threadIdx.x;
    const int ch = blockIdx.x;

    if (t < CEM) ceS[t] = char_table[ch * CEM + t];
    __syncthreads();

    if (t < OD) {
        const float* cw = conv_w + t * CEM;
        float a0 = 0.f, a1 = 0.f, a2 = 0.f, a3 = 0.f;
        #pragma unroll
        for (int e = 0; e < CEM; e += 4) {
            a0 = fmaf(cw[e + 0], ceS[e + 0], a0);
            a1 = fmaf(cw[e + 1], ceS[e + 1], a1);
            a2 = fmaf(cw[e + 2], ceS[e + 2], a2);
            a3 = fmaf(cw[e + 3], ceS[e + 3], a3);
        }
        U[t] = (a0 + a1) + (a2 + a3);
    }
    __syncthreads();

    if (t < OD) {
        const float* lw = lin_w + t * OD;
        float a0 = 0.f, a1 = 0.f, a2 = 0.f, a3 = 0.f;
        #pragma unroll 5
        for (int j = 0; j < OD; j += 4) {
            a0 = fmaf(lw[j + 0], U[j + 0], a0);
            a1 = fmaf(lw[j + 1], U[j + 1], a1);
            a2 = fmaf(lw[j + 2], U[j + 2], a2);
            a3 = fmaf(lw[j + 3], U[j + 3], a3);
        }
        ws[ch * OD + t] = (a0 + a1) + (a2 + a3);

        if (ch == 0) {
            float b0 = lin_b[t], b1 = 0.f, b2 = 0.f, b3 = 0.f;
            #pragma unroll 5
            for (int j = 0; j < OD; j += 4) {
                b0 = fmaf(lw[j + 0], conv_b[j + 0], b0);
                b1 = fmaf(lw[j + 1], conv_b[j + 1], b1);
                b2 = fmaf(lw[j + 2], conv_b[j + 2], b2);
                b3 = fmaf(lw[j + 3], conv_b[j + 3], b3);
            }
            ws[NCH * OD + t] = (b0 + b1) + (b2 + b3);
        }
    }
}

// One wave per word, 4 waves/block. Lane l (<50) owns outputs o=2l,2l+1 (float2):
// halves T-gather issue count vs the scalar version; single 400B output store.
// Junk lanes (50..63) load in-bounds garbage and never store.
// Wave-uniform len: full char-groups take the cndmask-free path.
__global__ __launch_bounds__(256) void fused_embed(
        const int*   __restrict__ word_tokens,
        const int*   __restrict__ char_ids,
        const int*   __restrict__ char_lens,
        const float* __restrict__ glove,
        const float* __restrict__ ws,
        float*       __restrict__ out) {
    const int wave = threadIdx.x >> 6;
    const int lane = threadIdx.x & 63;
    const int word = blockIdx.x * 4 + wave;

    const int tok = word_tokens[word];              // wave-uniform
    const int len = char_lens[word];                // wave-uniform, >= 1

    const int4* cid4 = (const int4*)(char_ids + (size_t)word * LW);
    const int4 i0 = cid4[0], i1 = cid4[1], i2 = cid4[2], i3 = cid4[3];

    // glove passthrough: 75 float4, coalesced
    const float4* g4 = (const float4*)(glove + (size_t)tok * GD);
    float4 g0 = g4[lane];
    float4 g1;
    const bool tail = lane < (GD / 4 - 64);         // lanes 0..10
    if (tail) g1 = g4[64 + lane];

    // bias float2 (lanes >= 50 read pad region 12900..12927 — in-bounds junk)
    const bool act = lane < OD / 2;                 // lanes 0..49
    const float2 cb = ((const float2*)(ws + NCH * OD))[lane];

    float2 acc = {0.f, 0.f};

    // T rows as float2: row base ws + ch*100 is 8B-aligned (100 even).
    // Junk lanes: worst case ch=127 -> floats 12700+2*63+1 = 12827 < 12900. Safe.
#define TPTR(id) ((const float2*)(ws + (id) * OD))
#define LOADG(iv, a, b, c, d) \
    float2 a = TPTR((iv).x)[lane], b = TPTR((iv).y)[lane], \
           c = TPTR((iv).z)[lane], d = TPTR((iv).w)[lane];
#define ADDF(a, b, c, d) { \
    acc.x += ((a.x + b.x) + (c.x + d.x)); \
    acc.y += ((a.y + b.y) + (c.y + d.y)); }
#define ADDP(base, a, b, c, d) { \
    acc.x += ((base) + 0 < len) ? a.x : 0.f;  acc.y += ((base) + 0 < len) ? a.y : 0.f; \
    acc.x += ((base) + 1 < len) ? b.x : 0.f;  acc.y += ((base) + 1 < len) ? b.y : 0.f; \
    acc.x += ((base) + 2 < len) ? c.x : 0.f;  acc.y += ((base) + 2 < len) ? c.y : 0.f; \
    acc.x += ((base) + 3 < len) ? d.x : 0.f;  acc.y += ((base) + 3 < len) ? d.y : 0.f; }

    {
        LOADG(i0, v0, v1, v2, v3)
        if (len >= 4) ADDF(v0, v1, v2, v3) else ADDP(0, v0, v1, v2, v3)
    }
    if (len > 4) {
        LOADG(i1, v0, v1, v2, v3)
        if (len >= 8) ADDF(v0, v1, v2, v3) else ADDP(4, v0, v1, v2, v3)
    }
    if (len > 8) {
        LOADG(i2, v0, v1, v2, v3)
        if (len >= 12) ADDF(v0, v1, v2, v3) else ADDP(8, v0, v1, v2, v3)
    }
    if (len > 12) {
        LOADG(i3, v0, v1, v2, v3)
        if (len >= 16) ADDF(v0, v1, v2, v3) else ADDP(12, v0, v1, v2, v3)
    }
#undef TPTR
#undef LOADG
#undef ADDF
#undef ADDP

    // glove store (after T loads are issued)
    float4* d4 = (float4*)(out + (size_t)word * (GD + OD));
    d4[lane] = g0;
    if (tail) d4[64 + lane] = g1;

    const float inv = 1.f / (float)len;
    if (act) {
        float2 r;
        r.x = fmaf(acc.x, inv, cb.x);
        r.y = fmaf(acc.y, inv, cb.y);
        float2* co2 = (float2*)(out + (size_t)word * (GD + OD) + GD);
        co2[lane] = r;                               // 400 B coalesced
    }
}

extern "C" void kernel_launch(void* const* d_in, const int* in_sizes, int n_in,
                              void* d_out, int out_size, void* d_ws, size_t ws_size,
                              hipStream_t stream) {
    const int*   word_tokens = (const int*)  d_in[0];
    const int*   char_ids    = (const int*)  d_in[1];
    const int*   char_lens   = (const int*)  d_in[2];
    const float* glove       = (const float*)d_in[3];
    const float* char_table  = (const float*)d_in[4];
    const float* conv_w      = (const float*)d_in[5];
    const float* conv_b      = (const float*)d_in[6];
    const float* lin_w       = (const float*)d_in[7];
    const float* lin_b       = (const float*)d_in[8];
    float* out = (float*)d_out;
    float* ws  = (float*)d_ws;   // needs 12928 floats ~= 51.7 KB

    precompute_T<<<NCH, 128, 0, stream>>>(char_table, conv_w, conv_b, lin_w, lin_b, ws);

    fused_embed<<<NW / 4, 256, 0, stream>>>(
        word_tokens, char_ids, char_lens, glove, ws, out);
}